// Round 1
// baseline (2037.459 us; speedup 1.0000x reference)
//
#include <hip/hip_runtime.h>
#include <math.h>

#define NN 50000
#define NE 1600000

__device__ __forceinline__ float celu_f(float v) {
    return v > 0.0f ? v : expm1f(v);
}

__global__ __launch_bounds__(256) void zero_kernel(float4* __restrict__ p, int n4) {
    int i = blockIdx.x * blockDim.x + threadIdx.x;
    if (i < n4) p[i] = make_float4(0.f, 0.f, 0.f, 0.f);
}

// One thread per edge. Weights in LDS (wave-broadcast reads). h[64] in registers.
// Scatter via atomicMax on uint bit-pattern (messages are >= 0 after relu).
__global__ __launch_bounds__(256) void edge_kernel(
    const float* __restrict__ x, const float* __restrict__ pos,
    const int* __restrict__ ei,
    const float* __restrict__ fw1, const float* __restrict__ fb1,
    const float* __restrict__ fw2, const float* __restrict__ fb2,
    unsigned int* __restrict__ aggr)
{
    __shared__ __align__(16) float s_w1[6 * 64];
    __shared__ __align__(16) float s_b1[64];
    __shared__ __align__(16) float s_w2[64 * 64];
    __shared__ __align__(16) float s_b2[64];

    const int tid = threadIdx.x;
    for (int i = tid; i < 6 * 64; i += 256) s_w1[i] = fw1[i];
    for (int i = tid; i < 64 * 64; i += 256) s_w2[i] = fw2[i];
    if (tid < 64) { s_b1[tid] = fb1[tid]; s_b2[tid] = fb2[tid]; }
    __syncthreads();

    const int e = blockIdx.x * 256 + tid;
    if (e >= NE) return;

    const int s = ei[e];
    const int d = ei[NE + e];

    float in[6];
    in[0] = x[s * 3 + 0];
    in[1] = x[s * 3 + 1];
    in[2] = x[s * 3 + 2];
    in[3] = pos[s * 3 + 0] - pos[d * 3 + 0];
    in[4] = pos[s * 3 + 1] - pos[d * 3 + 1];
    in[5] = pos[s * 3 + 2] - pos[d * 3 + 2];

    // h = celu(in @ fw1 + fb1), fw1 is [6][64] row-major
    float h[64];
#pragma unroll
    for (int k = 0; k < 64; k += 4) {
        float4 acc = *(const float4*)&s_b1[k];
#pragma unroll
        for (int i = 0; i < 6; ++i) {
            float4 w = *(const float4*)&s_w1[i * 64 + k];
            acc.x = fmaf(in[i], w.x, acc.x);
            acc.y = fmaf(in[i], w.y, acc.y);
            acc.z = fmaf(in[i], w.z, acc.z);
            acc.w = fmaf(in[i], w.w, acc.w);
        }
        h[k + 0] = celu_f(acc.x);
        h[k + 1] = celu_f(acc.y);
        h[k + 2] = celu_f(acc.z);
        h[k + 3] = celu_f(acc.w);
    }

    // msg = relu(h @ fw2 + fb2), fw2 is [64][64] row-major; scatter-max to aggr[d]
    unsigned int* arow = aggr + (size_t)d * 64;
    for (int o = 0; o < 64; o += 4) {
        float4 acc = *(const float4*)&s_b2[o];
#pragma unroll
        for (int k = 0; k < 64; ++k) {
            float4 w = *(const float4*)&s_w2[k * 64 + o];
            acc.x = fmaf(h[k], w.x, acc.x);
            acc.y = fmaf(h[k], w.y, acc.y);
            acc.z = fmaf(h[k], w.z, acc.z);
            acc.w = fmaf(h[k], w.w, acc.w);
        }
        if (acc.x > 0.f) atomicMax(&arow[o + 0], __float_as_uint(acc.x));
        if (acc.y > 0.f) atomicMax(&arow[o + 1], __float_as_uint(acc.y));
        if (acc.z > 0.f) atomicMax(&arow[o + 2], __float_as_uint(acc.z));
        if (acc.w > 0.f) atomicMax(&arow[o + 3], __float_as_uint(acc.w));
    }
}

// One thread per node. Reads aggr row (bit-patterns of non-negative floats, so a
// plain float view is valid; empty rows stayed 0), computes update MLP, writes the
// final output IN PLACE over the aggr buffer (each thread owns its row; all reads
// of a[] happen before any write).
__global__ __launch_bounds__(256) void node_kernel(
    const float* __restrict__ x,
    float* io,   // d_out: aggr in, final out
    const float* __restrict__ gw1, const float* __restrict__ gb1,
    const float* __restrict__ gw2, const float* __restrict__ gb2)
{
    __shared__ __align__(16) float s_w1[67 * 64];
    __shared__ __align__(16) float s_b1[64];
    __shared__ __align__(16) float s_w2[64 * 64];
    __shared__ __align__(16) float s_b2[64];

    const int tid = threadIdx.x;
    for (int i = tid; i < 67 * 64; i += 256) s_w1[i] = gw1[i];
    for (int i = tid; i < 64 * 64; i += 256) s_w2[i] = gw2[i];
    if (tid < 64) { s_b1[tid] = gb1[tid]; s_b2[tid] = gb2[tid]; }
    __syncthreads();

    const int n = blockIdx.x * 256 + tid;
    if (n >= NN) return;

    float a[64];
#pragma unroll
    for (int k = 0; k < 64; k += 4) {
        float4 v = *(const float4*)&io[(size_t)n * 64 + k];
        a[k + 0] = v.x; a[k + 1] = v.y; a[k + 2] = v.z; a[k + 3] = v.w;
    }
    float xv[3];
    xv[0] = x[n * 3 + 0];
    xv[1] = x[n * 3 + 1];
    xv[2] = x[n * 3 + 2];

    // u = celu([a, x] @ gw1 + gb1), gw1 is [67][64]: rows 0..63 = aggr, 64..66 = x
    float u[64];
    for (int j = 0; j < 64; j += 4) {
        float4 acc = *(const float4*)&s_b1[j];
#pragma unroll
        for (int k = 0; k < 64; ++k) {
            float4 w = *(const float4*)&s_w1[k * 64 + j];
            acc.x = fmaf(a[k], w.x, acc.x);
            acc.y = fmaf(a[k], w.y, acc.y);
            acc.z = fmaf(a[k], w.z, acc.z);
            acc.w = fmaf(a[k], w.w, acc.w);
        }
#pragma unroll
        for (int i = 0; i < 3; ++i) {
            float4 w = *(const float4*)&s_w1[(64 + i) * 64 + j];
            acc.x = fmaf(xv[i], w.x, acc.x);
            acc.y = fmaf(xv[i], w.y, acc.y);
            acc.z = fmaf(xv[i], w.z, acc.z);
            acc.w = fmaf(xv[i], w.w, acc.w);
        }
        u[j + 0] = celu_f(acc.x);
        u[j + 1] = celu_f(acc.y);
        u[j + 2] = celu_f(acc.z);
        u[j + 3] = celu_f(acc.w);
    }

    // out = celu(u @ gw2 + gb2)
    float* orow = &io[(size_t)n * 64];
    for (int j = 0; j < 64; j += 4) {
        float4 acc = *(const float4*)&s_b2[j];
#pragma unroll
        for (int k = 0; k < 64; ++k) {
            float4 w = *(const float4*)&s_w2[k * 64 + j];
            acc.x = fmaf(u[k], w.x, acc.x);
            acc.y = fmaf(u[k], w.y, acc.y);
            acc.z = fmaf(u[k], w.z, acc.z);
            acc.w = fmaf(u[k], w.w, acc.w);
        }
        float4 r;
        r.x = celu_f(acc.x);
        r.y = celu_f(acc.y);
        r.z = celu_f(acc.z);
        r.w = celu_f(acc.w);
        *(float4*)&orow[j] = r;
    }
}

extern "C" void kernel_launch(void* const* d_in, const int* in_sizes, int n_in,
                              void* d_out, int out_size, void* d_ws, size_t ws_size,
                              hipStream_t stream) {
    const float* x   = (const float*)d_in[0];
    const float* pos = (const float*)d_in[1];
    const int*   ei  = (const int*)d_in[2];
    const float* fw1 = (const float*)d_in[3];
    const float* fb1 = (const float*)d_in[4];
    const float* fw2 = (const float*)d_in[5];
    const float* fb2 = (const float*)d_in[6];
    const float* gw1 = (const float*)d_in[7];
    const float* gb1 = (const float*)d_in[8];
    const float* gw2 = (const float*)d_in[9];
    const float* gb2 = (const float*)d_in[10];
    float* out = (float*)d_out;

    const int n4 = NN * 64 / 4;
    zero_kernel<<<(n4 + 255) / 256, 256, 0, stream>>>((float4*)out, n4);
    edge_kernel<<<NE / 256, 256, 0, stream>>>(x, pos, ei, fw1, fb1, fw2, fb2,
                                              (unsigned int*)out);
    node_kernel<<<(NN + 255) / 256, 256, 0, stream>>>(x, out, gw1, gb1, gw2, gb2);
}

// Round 2
// 1551.856 us; speedup vs baseline: 1.3129x; 1.3129x over previous
//
#include <hip/hip_runtime.h>
#include <hip/hip_fp16.h>
#include <math.h>

#define NN 50000
#define NE 1600000

typedef unsigned int u32;

__device__ __forceinline__ float celu_f(float v) {
    return v > 0.0f ? v : expm1f(v);
}

// ======================= sort machinery =======================

__global__ __launch_bounds__(256) void zero_u32_kernel(u32* __restrict__ p, int n) {
    int i = blockIdx.x * 256 + threadIdx.x;
    if (i < n) p[i] = 0u;
}

__global__ __launch_bounds__(256) void hist_kernel(const int* __restrict__ ei,
                                                   u32* __restrict__ cnt) {
    int e = blockIdx.x * 256 + threadIdx.x;
    if (e < NE) atomicAdd(&cnt[ei[NE + e]], 1u);
}

// single-block exclusive scan over NN counts -> off[0..NN], plus cursor copy
__global__ __launch_bounds__(1024) void scan_kernel(const u32* __restrict__ cnt,
                                                    u32* __restrict__ off,
                                                    u32* __restrict__ cur) {
    __shared__ u32 s[1024];
    __shared__ u32 carry;
    const int tid = threadIdx.x;
    if (tid == 0) carry = 0u;
    __syncthreads();
    for (int base = 0; base < NN; base += 1024) {
        u32 v = (base + tid < NN) ? cnt[base + tid] : 0u;
        s[tid] = v;
        __syncthreads();
        for (int d = 1; d < 1024; d <<= 1) {
            u32 t = (tid >= d) ? s[tid - d] : 0u;
            __syncthreads();
            s[tid] += t;
            __syncthreads();
        }
        u32 excl = s[tid] - v + carry;
        if (base + tid < NN) { off[base + tid] = excl; cur[base + tid] = excl; }
        __syncthreads();
        if (tid == 1023) carry += s[1023];
        __syncthreads();
    }
    if (tid == 0) off[NN] = carry;   // == NE
}

__global__ __launch_bounds__(256) void scatter_kernel(const int* __restrict__ ei,
                                                      u32* __restrict__ cur,
                                                      u32* __restrict__ eid) {
    int e = blockIdx.x * 256 + threadIdx.x;
    if (e < NE) {
        int d = ei[NE + e];
        u32 p = atomicAdd(&cur[d], 1u);
        eid[p] = (u32)e;
    }
}

// ======================= main path =======================

// One thread per SORTED edge slot. Computes f-MLP (layer2 pre-relu) and streams
// the 64-ch message row to msg[i] as fp16 (contiguous, coalesced, no atomics).
// ReLU is deferred to the gather (max with 0-init is equivalent).
__global__ __launch_bounds__(256) void edge_sorted_kernel(
    const float* __restrict__ x, const float* __restrict__ pos,
    const int* __restrict__ ei, const u32* __restrict__ eid,
    const float* __restrict__ fw1, const float* __restrict__ fb1,
    const float* __restrict__ fw2, const float* __restrict__ fb2,
    __half* __restrict__ msg)
{
    __shared__ __align__(16) float s_w1[6 * 64];
    __shared__ __align__(16) float s_b1[64];
    __shared__ __align__(16) float s_w2[64 * 64];
    __shared__ __align__(16) float s_b2[64];

    const int tid = threadIdx.x;
    for (int i = tid; i < 6 * 64; i += 256) s_w1[i] = fw1[i];
    for (int i = tid; i < 64 * 64; i += 256) s_w2[i] = fw2[i];
    if (tid < 64) { s_b1[tid] = fb1[tid]; s_b2[tid] = fb2[tid]; }
    __syncthreads();

    const int i = blockIdx.x * 256 + tid;   // NE % 256 == 0
    const int e = (int)eid[i];
    const int s = ei[e];
    const int d = ei[NE + e];

    float in[6];
    in[0] = x[s * 3 + 0];
    in[1] = x[s * 3 + 1];
    in[2] = x[s * 3 + 2];
    in[3] = pos[s * 3 + 0] - pos[d * 3 + 0];
    in[4] = pos[s * 3 + 1] - pos[d * 3 + 1];
    in[5] = pos[s * 3 + 2] - pos[d * 3 + 2];

    float h[64];
#pragma unroll
    for (int k = 0; k < 64; k += 4) {
        float4 acc = *(const float4*)&s_b1[k];
#pragma unroll
        for (int q = 0; q < 6; ++q) {
            float4 w = *(const float4*)&s_w1[q * 64 + k];
            acc.x = fmaf(in[q], w.x, acc.x);
            acc.y = fmaf(in[q], w.y, acc.y);
            acc.z = fmaf(in[q], w.z, acc.z);
            acc.w = fmaf(in[q], w.w, acc.w);
        }
        h[k + 0] = celu_f(acc.x);
        h[k + 1] = celu_f(acc.y);
        h[k + 2] = celu_f(acc.z);
        h[k + 3] = celu_f(acc.w);
    }

    __half* row = msg + (size_t)i * 64;
    for (int o = 0; o < 64; o += 8) {
        float4 a0 = *(const float4*)&s_b2[o];
        float4 a1 = *(const float4*)&s_b2[o + 4];
#pragma unroll
        for (int k = 0; k < 64; ++k) {
            float hk = h[k];
            float4 w0 = *(const float4*)&s_w2[k * 64 + o];
            float4 w1 = *(const float4*)&s_w2[k * 64 + o + 4];
            a0.x = fmaf(hk, w0.x, a0.x);
            a0.y = fmaf(hk, w0.y, a0.y);
            a0.z = fmaf(hk, w0.z, a0.z);
            a0.w = fmaf(hk, w0.w, a0.w);
            a1.x = fmaf(hk, w1.x, a1.x);
            a1.y = fmaf(hk, w1.y, a1.y);
            a1.z = fmaf(hk, w1.z, a1.z);
            a1.w = fmaf(hk, w1.w, a1.w);
        }
        union { uint4 u; __half hh[8]; } pk;
        pk.hh[0] = __float2half(a0.x);
        pk.hh[1] = __float2half(a0.y);
        pk.hh[2] = __float2half(a0.z);
        pk.hh[3] = __float2half(a0.w);
        pk.hh[4] = __float2half(a1.x);
        pk.hh[5] = __float2half(a1.y);
        pk.hh[6] = __float2half(a1.z);
        pk.hh[7] = __float2half(a1.w);
        *(uint4*)(row + o) = pk.u;
    }
}

// Half-wave (32 lanes) per node: max-reduce the node's contiguous message
// segment. lane handles channels 2*lane, 2*lane+1. acc init 0 == deferred relu
// and empty-segment semantics.
__global__ __launch_bounds__(256) void gather_kernel(
    const __half* __restrict__ msg, const u32* __restrict__ off,
    float* __restrict__ aggr)
{
    const int n = blockIdx.x * 8 + (threadIdx.x >> 5);
    const int lane = threadIdx.x & 31;
    if (n >= NN) return;
    const u32 b = off[n];
    const u32 t = off[n + 1];
    const __half2* rows = (const __half2*)msg;
    float2 acc = make_float2(0.f, 0.f);
    for (u32 j = b; j < t; ++j) {
        __half2 hv = rows[(size_t)j * 32 + lane];
        float2 f = __half22float2(hv);
        acc.x = fmaxf(acc.x, f.x);
        acc.y = fmaxf(acc.y, f.y);
    }
    *(float2*)&aggr[(size_t)n * 64 + lane * 2] = acc;
}

// ======================= node update MLP =======================

__global__ __launch_bounds__(256) void node_kernel(
    const float* __restrict__ x,
    float* io,   // d_out: aggr in, final out (in place, thread owns its row)
    const float* __restrict__ gw1, const float* __restrict__ gb1,
    const float* __restrict__ gw2, const float* __restrict__ gb2)
{
    __shared__ __align__(16) float s_w1[67 * 64];
    __shared__ __align__(16) float s_b1[64];
    __shared__ __align__(16) float s_w2[64 * 64];
    __shared__ __align__(16) float s_b2[64];

    const int tid = threadIdx.x;
    for (int i = tid; i < 67 * 64; i += 256) s_w1[i] = gw1[i];
    for (int i = tid; i < 64 * 64; i += 256) s_w2[i] = gw2[i];
    if (tid < 64) { s_b1[tid] = gb1[tid]; s_b2[tid] = gb2[tid]; }
    __syncthreads();

    const int n = blockIdx.x * 256 + tid;
    if (n >= NN) return;

    float a[64];
#pragma unroll
    for (int k = 0; k < 64; k += 4) {
        float4 v = *(const float4*)&io[(size_t)n * 64 + k];
        a[k + 0] = v.x; a[k + 1] = v.y; a[k + 2] = v.z; a[k + 3] = v.w;
    }
    float xv[3];
    xv[0] = x[n * 3 + 0];
    xv[1] = x[n * 3 + 1];
    xv[2] = x[n * 3 + 2];

    float u[64];
    for (int j = 0; j < 64; j += 4) {
        float4 acc = *(const float4*)&s_b1[j];
#pragma unroll
        for (int k = 0; k < 64; ++k) {
            float4 w = *(const float4*)&s_w1[k * 64 + j];
            acc.x = fmaf(a[k], w.x, acc.x);
            acc.y = fmaf(a[k], w.y, acc.y);
            acc.z = fmaf(a[k], w.z, acc.z);
            acc.w = fmaf(a[k], w.w, acc.w);
        }
#pragma unroll
        for (int q = 0; q < 3; ++q) {
            float4 w = *(const float4*)&s_w1[(64 + q) * 64 + j];
            acc.x = fmaf(xv[q], w.x, acc.x);
            acc.y = fmaf(xv[q], w.y, acc.y);
            acc.z = fmaf(xv[q], w.z, acc.z);
            acc.w = fmaf(xv[q], w.w, acc.w);
        }
        u[j + 0] = celu_f(acc.x);
        u[j + 1] = celu_f(acc.y);
        u[j + 2] = celu_f(acc.z);
        u[j + 3] = celu_f(acc.w);
    }

    float* orow = &io[(size_t)n * 64];
    for (int j = 0; j < 64; j += 4) {
        float4 acc = *(const float4*)&s_b2[j];
#pragma unroll
        for (int k = 0; k < 64; ++k) {
            float4 w = *(const float4*)&s_w2[k * 64 + j];
            acc.x = fmaf(u[k], w.x, acc.x);
            acc.y = fmaf(u[k], w.y, acc.y);
            acc.z = fmaf(u[k], w.z, acc.z);
            acc.w = fmaf(u[k], w.w, acc.w);
        }
        float4 r;
        r.x = celu_f(acc.x);
        r.y = celu_f(acc.y);
        r.z = celu_f(acc.z);
        r.w = celu_f(acc.w);
        *(float4*)&orow[j] = r;
    }
}

// ======================= fallback (R1 atomic path) =======================

__global__ __launch_bounds__(256) void zero_kernel(float4* __restrict__ p, int n4) {
    int i = blockIdx.x * blockDim.x + threadIdx.x;
    if (i < n4) p[i] = make_float4(0.f, 0.f, 0.f, 0.f);
}

__global__ __launch_bounds__(256) void edge_atomic_kernel(
    const float* __restrict__ x, const float* __restrict__ pos,
    const int* __restrict__ ei,
    const float* __restrict__ fw1, const float* __restrict__ fb1,
    const float* __restrict__ fw2, const float* __restrict__ fb2,
    unsigned int* __restrict__ aggr)
{
    __shared__ __align__(16) float s_w1[6 * 64];
    __shared__ __align__(16) float s_b1[64];
    __shared__ __align__(16) float s_w2[64 * 64];
    __shared__ __align__(16) float s_b2[64];

    const int tid = threadIdx.x;
    for (int i = tid; i < 6 * 64; i += 256) s_w1[i] = fw1[i];
    for (int i = tid; i < 64 * 64; i += 256) s_w2[i] = fw2[i];
    if (tid < 64) { s_b1[tid] = fb1[tid]; s_b2[tid] = fb2[tid]; }
    __syncthreads();

    const int e = blockIdx.x * 256 + tid;
    if (e >= NE) return;

    const int s = ei[e];
    const int d = ei[NE + e];

    float in[6];
    in[0] = x[s * 3 + 0];
    in[1] = x[s * 3 + 1];
    in[2] = x[s * 3 + 2];
    in[3] = pos[s * 3 + 0] - pos[d * 3 + 0];
    in[4] = pos[s * 3 + 1] - pos[d * 3 + 1];
    in[5] = pos[s * 3 + 2] - pos[d * 3 + 2];

    float h[64];
#pragma unroll
    for (int k = 0; k < 64; k += 4) {
        float4 acc = *(const float4*)&s_b1[k];
#pragma unroll
        for (int q = 0; q < 6; ++q) {
            float4 w = *(const float4*)&s_w1[q * 64 + k];
            acc.x = fmaf(in[q], w.x, acc.x);
            acc.y = fmaf(in[q], w.y, acc.y);
            acc.z = fmaf(in[q], w.z, acc.z);
            acc.w = fmaf(in[q], w.w, acc.w);
        }
        h[k + 0] = celu_f(acc.x);
        h[k + 1] = celu_f(acc.y);
        h[k + 2] = celu_f(acc.z);
        h[k + 3] = celu_f(acc.w);
    }

    unsigned int* arow = aggr + (size_t)d * 64;
    for (int o = 0; o < 64; o += 4) {
        float4 acc = *(const float4*)&s_b2[o];
#pragma unroll
        for (int k = 0; k < 64; ++k) {
            float4 w = *(const float4*)&s_w2[k * 64 + o];
            acc.x = fmaf(h[k], w.x, acc.x);
            acc.y = fmaf(h[k], w.y, acc.y);
            acc.z = fmaf(h[k], w.z, acc.z);
            acc.w = fmaf(h[k], w.w, acc.w);
        }
        if (acc.x > 0.f) atomicMax(&arow[o + 0], __float_as_uint(acc.x));
        if (acc.y > 0.f) atomicMax(&arow[o + 1], __float_as_uint(acc.y));
        if (acc.z > 0.f) atomicMax(&arow[o + 2], __float_as_uint(acc.z));
        if (acc.w > 0.f) atomicMax(&arow[o + 3], __float_as_uint(acc.w));
    }
}

// ======================= launcher =======================

extern "C" void kernel_launch(void* const* d_in, const int* in_sizes, int n_in,
                              void* d_out, int out_size, void* d_ws, size_t ws_size,
                              hipStream_t stream) {
    const float* x   = (const float*)d_in[0];
    const float* pos = (const float*)d_in[1];
    const int*   ei  = (const int*)d_in[2];
    const float* fw1 = (const float*)d_in[3];
    const float* fb1 = (const float*)d_in[4];
    const float* fw2 = (const float*)d_in[5];
    const float* fb2 = (const float*)d_in[6];
    const float* gw1 = (const float*)d_in[7];
    const float* gb1 = (const float*)d_in[8];
    const float* gw2 = (const float*)d_in[9];
    const float* gb2 = (const float*)d_in[10];
    float* out = (float*)d_out;

    auto al = [](size_t v) { return (v + 255) & ~(size_t)255; };
    const size_t o_cnt = 0;
    const size_t o_off = al(o_cnt + (size_t)NN * 4);
    const size_t o_cur = al(o_off + (size_t)(NN + 1) * 4);
    const size_t o_eid = al(o_cur + (size_t)NN * 4);
    const size_t o_msg = al(o_eid + (size_t)NE * 4);
    const size_t need  = o_msg + (size_t)NE * 64 * 2;

    if (ws_size >= need) {
        char* w = (char*)d_ws;
        u32*    cnt = (u32*)(w + o_cnt);
        u32*    off = (u32*)(w + o_off);
        u32*    cur = (u32*)(w + o_cur);
        u32*    eid = (u32*)(w + o_eid);
        __half* msg = (__half*)(w + o_msg);

        zero_u32_kernel<<<(NN + 255) / 256, 256, 0, stream>>>(cnt, NN);
        hist_kernel<<<NE / 256, 256, 0, stream>>>(ei, cnt);
        scan_kernel<<<1, 1024, 0, stream>>>(cnt, off, cur);
        scatter_kernel<<<NE / 256, 256, 0, stream>>>(ei, cur, eid);
        edge_sorted_kernel<<<NE / 256, 256, 0, stream>>>(x, pos, ei, eid,
                                                         fw1, fb1, fw2, fb2, msg);
        gather_kernel<<<(NN + 7) / 8, 256, 0, stream>>>(msg, off, out);
        node_kernel<<<(NN + 255) / 256, 256, 0, stream>>>(x, out, gw1, gb1, gw2, gb2);
    } else {
        // fallback: R1 atomic path (ws too small for message materialization)
        const int n4 = NN * 64 / 4;
        zero_kernel<<<(n4 + 255) / 256, 256, 0, stream>>>((float4*)out, n4);
        edge_atomic_kernel<<<NE / 256, 256, 0, stream>>>(x, pos, ei, fw1, fb1,
                                                         fw2, fb2, (unsigned int*)out);
        node_kernel<<<(NN + 255) / 256, 256, 0, stream>>>(x, out, gw1, gb1, gw2, gb2);
    }
}

// Round 3
// 495.571 us; speedup vs baseline: 4.1113x; 3.1314x over previous
//
#include <hip/hip_runtime.h>
#include <hip/hip_fp16.h>
#include <math.h>

#define NN 50000
#define NE 1600000

typedef unsigned int u32;
typedef _Float16 f16x8 __attribute__((ext_vector_type(8)));
typedef float f32x4 __attribute__((ext_vector_type(4)));

__device__ __forceinline__ float celu_f(float v) {
    return v > 0.0f ? v : expm1f(v);
}

// ======================= sort machinery =======================

__global__ __launch_bounds__(256) void zero_u32_kernel(u32* __restrict__ p, int n) {
    int i = blockIdx.x * 256 + threadIdx.x;
    if (i < n) p[i] = 0u;
}

__global__ __launch_bounds__(256) void hist_kernel(const int* __restrict__ ei,
                                                   u32* __restrict__ cnt) {
    int e = blockIdx.x * 256 + threadIdx.x;
    if (e < NE) atomicAdd(&cnt[ei[NE + e]], 1u);
}

// 3-phase parallel scan: per-block scan -> scan of block sums -> add offsets
__global__ __launch_bounds__(256) void scan1_kernel(const u32* __restrict__ cnt,
                                                    u32* __restrict__ excl,
                                                    u32* __restrict__ bsum) {
    __shared__ u32 s[256];
    const int tid = threadIdx.x;
    const int i = blockIdx.x * 256 + tid;
    u32 v = (i < NN) ? cnt[i] : 0u;
    s[tid] = v;
    __syncthreads();
    for (int d = 1; d < 256; d <<= 1) {
        u32 t = (tid >= d) ? s[tid - d] : 0u;
        __syncthreads();
        s[tid] += t;
        __syncthreads();
    }
    if (i < NN) excl[i] = s[tid] - v;
    if (tid == 255) bsum[blockIdx.x] = s[255];
}

__global__ __launch_bounds__(256) void scan2_kernel(u32* __restrict__ bsum,
                                                    u32* __restrict__ bexcl, int nb) {
    __shared__ u32 s[256];
    const int tid = threadIdx.x;
    u32 v = (tid < nb) ? bsum[tid] : 0u;
    s[tid] = v;
    __syncthreads();
    for (int d = 1; d < 256; d <<= 1) {
        u32 t = (tid >= d) ? s[tid - d] : 0u;
        __syncthreads();
        s[tid] += t;
        __syncthreads();
    }
    if (tid < nb) bexcl[tid] = s[tid] - v;
}

__global__ __launch_bounds__(256) void scan3_kernel(const u32* __restrict__ excl,
                                                    const u32* __restrict__ bexcl,
                                                    u32* __restrict__ off,
                                                    u32* __restrict__ cur) {
    const int i = blockIdx.x * 256 + threadIdx.x;
    if (i < NN) {
        u32 o = excl[i] + bexcl[blockIdx.x];
        off[i] = o;
        cur[i] = o;
    }
    if (i == 0) off[NN] = NE;
}

__global__ __launch_bounds__(256) void scatter_kernel(const int* __restrict__ ei,
                                                      u32* __restrict__ cur,
                                                      u32* __restrict__ eid) {
    int e = blockIdx.x * 256 + threadIdx.x;
    if (e < NE) {
        int d = ei[NE + e];
        u32 p = atomicAdd(&cur[d], 1u);
        eid[p] = (u32)e;
    }
}

// ======================= weight prep =======================

// w2t[n][k] = fw2[k][n] as f16 (A-operand, row-major [out-ch][k])
__global__ __launch_bounds__(256) void prep_w2t_kernel(const float* __restrict__ fw2,
                                                       __half* __restrict__ w2t) {
    int i = blockIdx.x * 256 + threadIdx.x;   // 4096
    int k = i >> 6, n = i & 63;
    w2t[n * 64 + k] = __float2half(fw2[k * 64 + n]);
}

// ======================= fused edge kernel (MFMA layer 2) =======================
//
// One thread per SORTED edge slot. Layer 1 (6->64) on VALU with LDS-broadcast
// weights. h -> f16 -> XOR-swizzled LDS tile [256 edges][8 chunks of 16B],
// stored chunk = c ^ (row & 7). Layer 2 (64->64) via mfma_f32_16x16x32_f16:
//   D[ch][edge] = W2^T[ch][k] * h^T[k][edge]
// A-frag: w2t row-major (row = lane&15 = ch tile row, 16B chunk at k-offset
// (lane>>4)*8 + kt*32). B-frag: h row-major from LDS (row = lane&15 = edge).
// D: col = lane&15 = edge, row = (lane>>4)*4 + reg = channel -> each lane owns
// 4 consecutive channels of one edge -> 8B coalesced global store.
__global__ __launch_bounds__(256) void edge_mfma_kernel(
    const float* __restrict__ x, const float* __restrict__ pos,
    const int* __restrict__ ei, const u32* __restrict__ eid,
    const float* __restrict__ fw1, const float* __restrict__ fb1,
    const __half* __restrict__ w2t, const float* __restrict__ fb2,
    __half* __restrict__ msg)
{
    __shared__ __align__(16) float s_w1[6 * 64];
    __shared__ __align__(16) float s_b1[64];
    __shared__ __align__(16) __half s_h[256 * 64];   // 32 KiB, swizzled

    const int tid = threadIdx.x;
    for (int i = tid; i < 6 * 64; i += 256) s_w1[i] = fw1[i];
    if (tid < 64) s_b1[tid] = fb1[tid];
    __syncthreads();

    const int i = blockIdx.x * 256 + tid;   // NE % 256 == 0
    const int e = (int)eid[i];
    const int s = ei[e];
    const int d = ei[NE + e];

    float in[6];
    in[0] = x[s * 3 + 0];
    in[1] = x[s * 3 + 1];
    in[2] = x[s * 3 + 2];
    in[3] = pos[s * 3 + 0] - pos[d * 3 + 0];
    in[4] = pos[s * 3 + 1] - pos[d * 3 + 1];
    in[5] = pos[s * 3 + 2] - pos[d * 3 + 2];

    // layer 1: per-8-channel chunk, celu, cvt f16, swizzled LDS write
#pragma unroll
    for (int c8 = 0; c8 < 8; ++c8) {
        float4 a0 = *(const float4*)&s_b1[c8 * 8];
        float4 a1 = *(const float4*)&s_b1[c8 * 8 + 4];
#pragma unroll
        for (int q = 0; q < 6; ++q) {
            const float iv = in[q];
            float4 w0 = *(const float4*)&s_w1[q * 64 + c8 * 8];
            float4 w1v = *(const float4*)&s_w1[q * 64 + c8 * 8 + 4];
            a0.x = fmaf(iv, w0.x, a0.x);
            a0.y = fmaf(iv, w0.y, a0.y);
            a0.z = fmaf(iv, w0.z, a0.z);
            a0.w = fmaf(iv, w0.w, a0.w);
            a1.x = fmaf(iv, w1v.x, a1.x);
            a1.y = fmaf(iv, w1v.y, a1.y);
            a1.z = fmaf(iv, w1v.z, a1.z);
            a1.w = fmaf(iv, w1v.w, a1.w);
        }
        union { uint4 u; __half2 h2[4]; } pk;
        pk.h2[0] = __floats2half2_rn(celu_f(a0.x), celu_f(a0.y));
        pk.h2[1] = __floats2half2_rn(celu_f(a0.z), celu_f(a0.w));
        pk.h2[2] = __floats2half2_rn(celu_f(a1.x), celu_f(a1.y));
        pk.h2[3] = __floats2half2_rn(celu_f(a1.z), celu_f(a1.w));
        const int sc = c8 ^ (tid & 7);
        *(uint4*)&s_h[(tid << 6) + (sc << 3)] = pk.u;
    }
    __syncthreads();

    // layer 2: MFMA
    const int l = tid & 63;
    const int wbase = tid & 192;         // wave's edge-row base within block
    const int lrow = l & 15;
    const int lhi = l >> 4;

    f16x8 afrag[4][2];
#pragma unroll
    for (int at = 0; at < 4; ++at)
#pragma unroll
        for (int kt = 0; kt < 2; ++kt)
            afrag[at][kt] = *(const f16x8*)(w2t + ((at * 16 + lrow) << 6) + kt * 32 + (lhi << 3));

    f32x4 bias[4];
#pragma unroll
    for (int at = 0; at < 4; ++at)
        bias[at] = *(const f32x4*)(fb2 + at * 16 + (lhi << 2));

    const size_t msgbase = (size_t)blockIdx.x * 256 * 64;
#pragma unroll
    for (int g = 0; g < 4; ++g) {
        const int rb = wbase + g * 16 + lrow;    // edge row within block
        f32x4 acc[4];
#pragma unroll
        for (int at = 0; at < 4; ++at) acc[at] = bias[at];
#pragma unroll
        for (int kt = 0; kt < 2; ++kt) {
            const int sc = (kt * 4 + lhi) ^ (rb & 7);
            f16x8 b = *(const f16x8*)&s_h[(rb << 6) + (sc << 3)];
            acc[0] = __builtin_amdgcn_mfma_f32_16x16x32_f16(afrag[0][kt], b, acc[0], 0, 0, 0);
            acc[1] = __builtin_amdgcn_mfma_f32_16x16x32_f16(afrag[1][kt], b, acc[1], 0, 0, 0);
            acc[2] = __builtin_amdgcn_mfma_f32_16x16x32_f16(afrag[2][kt], b, acc[2], 0, 0, 0);
            acc[3] = __builtin_amdgcn_mfma_f32_16x16x32_f16(afrag[3][kt], b, acc[3], 0, 0, 0);
        }
        __half* mrow = msg + msgbase + (size_t)rb * 64;
#pragma unroll
        for (int at = 0; at < 4; ++at) {
            union { uint2 u; __half2 h2[2]; } pk;
            pk.h2[0] = __floats2half2_rn(acc[at][0], acc[at][1]);
            pk.h2[1] = __floats2half2_rn(acc[at][2], acc[at][3]);
            *(uint2*)(mrow + at * 16 + (lhi << 2)) = pk.u;
        }
    }
}

// ======================= gather =======================

// Half-wave (32 lanes) per node: max-reduce contiguous message segment.
// 0-init == deferred relu + empty-segment semantics.
__global__ __launch_bounds__(256) void gather_kernel(
    const __half* __restrict__ msg, const u32* __restrict__ off,
    float* __restrict__ aggr)
{
    const int n = blockIdx.x * 8 + (threadIdx.x >> 5);
    const int lane = threadIdx.x & 31;
    if (n >= NN) return;
    const u32 b = off[n];
    const u32 t = off[n + 1];
    const __half2* rows = (const __half2*)msg;
    float2 m0 = make_float2(0.f, 0.f);
    float2 m1 = make_float2(0.f, 0.f);
    u32 j = b;
    for (; j + 2 <= t; j += 2) {
        __half2 ha = rows[(size_t)j * 32 + lane];
        __half2 hb = rows[(size_t)(j + 1) * 32 + lane];
        float2 fa = __half22float2(ha);
        float2 fb = __half22float2(hb);
        m0.x = fmaxf(m0.x, fa.x); m0.y = fmaxf(m0.y, fa.y);
        m1.x = fmaxf(m1.x, fb.x); m1.y = fmaxf(m1.y, fb.y);
    }
    if (j < t) {
        float2 fa = __half22float2(rows[(size_t)j * 32 + lane]);
        m0.x = fmaxf(m0.x, fa.x); m0.y = fmaxf(m0.y, fa.y);
    }
    m0.x = fmaxf(m0.x, m1.x); m0.y = fmaxf(m0.y, m1.y);
    *(float2*)&aggr[(size_t)n * 64 + lane * 2] = m0;
}

// ======================= node update MLP =======================

__global__ __launch_bounds__(256) void node_kernel(
    const float* __restrict__ x,
    float* io,   // d_out: aggr in, final out (in place, thread owns its row)
    const float* __restrict__ gw1, const float* __restrict__ gb1,
    const float* __restrict__ gw2, const float* __restrict__ gb2)
{
    __shared__ __align__(16) float s_w1[67 * 64];
    __shared__ __align__(16) float s_b1[64];
    __shared__ __align__(16) float s_w2[64 * 64];
    __shared__ __align__(16) float s_b2[64];

    const int tid = threadIdx.x;
    for (int i = tid; i < 67 * 64; i += 256) s_w1[i] = gw1[i];
    for (int i = tid; i < 64 * 64; i += 256) s_w2[i] = gw2[i];
    if (tid < 64) { s_b1[tid] = gb1[tid]; s_b2[tid] = gb2[tid]; }
    __syncthreads();

    const int n = blockIdx.x * 256 + tid;
    if (n >= NN) return;

    float a[64];
#pragma unroll
    for (int k = 0; k < 64; k += 4) {
        float4 v = *(const float4*)&io[(size_t)n * 64 + k];
        a[k + 0] = v.x; a[k + 1] = v.y; a[k + 2] = v.z; a[k + 3] = v.w;
    }
    float xv[3];
    xv[0] = x[n * 3 + 0];
    xv[1] = x[n * 3 + 1];
    xv[2] = x[n * 3 + 2];

    float u[64];
    for (int j = 0; j < 64; j += 4) {
        float4 acc = *(const float4*)&s_b1[j];
#pragma unroll
        for (int k = 0; k < 64; ++k) {
            float4 w = *(const float4*)&s_w1[k * 64 + j];
            acc.x = fmaf(a[k], w.x, acc.x);
            acc.y = fmaf(a[k], w.y, acc.y);
            acc.z = fmaf(a[k], w.z, acc.z);
            acc.w = fmaf(a[k], w.w, acc.w);
        }
#pragma unroll
        for (int q = 0; q < 3; ++q) {
            float4 w = *(const float4*)&s_w1[(64 + q) * 64 + j];
            acc.x = fmaf(xv[q], w.x, acc.x);
            acc.y = fmaf(xv[q], w.y, acc.y);
            acc.z = fmaf(xv[q], w.z, acc.z);
            acc.w = fmaf(xv[q], w.w, acc.w);
        }
        u[j + 0] = celu_f(acc.x);
        u[j + 1] = celu_f(acc.y);
        u[j + 2] = celu_f(acc.z);
        u[j + 3] = celu_f(acc.w);
    }

    float* orow = &io[(size_t)n * 64];
    for (int j = 0; j < 64; j += 4) {
        float4 acc = *(const float4*)&s_b2[j];
#pragma unroll
        for (int k = 0; k < 64; ++k) {
            float4 w = *(const float4*)&s_w2[k * 64 + j];
            acc.x = fmaf(u[k], w.x, acc.x);
            acc.y = fmaf(u[k], w.y, acc.y);
            acc.z = fmaf(u[k], w.z, acc.z);
            acc.w = fmaf(u[k], w.w, acc.w);
        }
        float4 r;
        r.x = celu_f(acc.x);
        r.y = celu_f(acc.y);
        r.z = celu_f(acc.z);
        r.w = celu_f(acc.w);
        *(float4*)&orow[j] = r;
    }
}

// ======================= fallback (atomic path) =======================

__global__ __launch_bounds__(256) void zero_kernel(float4* __restrict__ p, int n4) {
    int i = blockIdx.x * blockDim.x + threadIdx.x;
    if (i < n4) p[i] = make_float4(0.f, 0.f, 0.f, 0.f);
}

__global__ __launch_bounds__(256) void edge_atomic_kernel(
    const float* __restrict__ x, const float* __restrict__ pos,
    const int* __restrict__ ei,
    const float* __restrict__ fw1, const float* __restrict__ fb1,
    const float* __restrict__ fw2, const float* __restrict__ fb2,
    unsigned int* __restrict__ aggr)
{
    __shared__ __align__(16) float s_w1[6 * 64];
    __shared__ __align__(16) float s_b1[64];
    __shared__ __align__(16) float s_w2[64 * 64];
    __shared__ __align__(16) float s_b2[64];

    const int tid = threadIdx.x;
    for (int i = tid; i < 6 * 64; i += 256) s_w1[i] = fw1[i];
    for (int i = tid; i < 64 * 64; i += 256) s_w2[i] = fw2[i];
    if (tid < 64) { s_b1[tid] = fb1[tid]; s_b2[tid] = fb2[tid]; }
    __syncthreads();

    const int e = blockIdx.x * 256 + tid;
    if (e >= NE) return;

    const int s = ei[e];
    const int d = ei[NE + e];

    float in[6];
    in[0] = x[s * 3 + 0];
    in[1] = x[s * 3 + 1];
    in[2] = x[s * 3 + 2];
    in[3] = pos[s * 3 + 0] - pos[d * 3 + 0];
    in[4] = pos[s * 3 + 1] - pos[d * 3 + 1];
    in[5] = pos[s * 3 + 2] - pos[d * 3 + 2];

    float h[64];
#pragma unroll
    for (int k = 0; k < 64; k += 4) {
        float4 acc = *(const float4*)&s_b1[k];
#pragma unroll
        for (int q = 0; q < 6; ++q) {
            float4 w = *(const float4*)&s_w1[q * 64 + k];
            acc.x = fmaf(in[q], w.x, acc.x);
            acc.y = fmaf(in[q], w.y, acc.y);
            acc.z = fmaf(in[q], w.z, acc.z);
            acc.w = fmaf(in[q], w.w, acc.w);
        }
        h[k + 0] = celu_f(acc.x);
        h[k + 1] = celu_f(acc.y);
        h[k + 2] = celu_f(acc.z);
        h[k + 3] = celu_f(acc.w);
    }

    unsigned int* arow = aggr + (size_t)d * 64;
    for (int o = 0; o < 64; o += 4) {
        float4 acc = *(const float4*)&s_b2[o];
#pragma unroll
        for (int k = 0; k < 64; ++k) {
            float4 w = *(const float4*)&s_w2[k * 64 + o];
            acc.x = fmaf(h[k], w.x, acc.x);
            acc.y = fmaf(h[k], w.y, acc.y);
            acc.z = fmaf(h[k], w.z, acc.z);
            acc.w = fmaf(h[k], w.w, acc.w);
        }
        if (acc.x > 0.f) atomicMax(&arow[o + 0], __float_as_uint(acc.x));
        if (acc.y > 0.f) atomicMax(&arow[o + 1], __float_as_uint(acc.y));
        if (acc.z > 0.f) atomicMax(&arow[o + 2], __float_as_uint(acc.z));
        if (acc.w > 0.f) atomicMax(&arow[o + 3], __float_as_uint(acc.w));
    }
}

// ======================= launcher =======================

extern "C" void kernel_launch(void* const* d_in, const int* in_sizes, int n_in,
                              void* d_out, int out_size, void* d_ws, size_t ws_size,
                              hipStream_t stream) {
    const float* x   = (const float*)d_in[0];
    const float* pos = (const float*)d_in[1];
    const int*   ei  = (const int*)d_in[2];
    const float* fw1 = (const float*)d_in[3];
    const float* fb1 = (const float*)d_in[4];
    const float* fw2 = (const float*)d_in[5];
    const float* fb2 = (const float*)d_in[6];
    const float* gw1 = (const float*)d_in[7];
    const float* gb1 = (const float*)d_in[8];
    const float* gw2 = (const float*)d_in[9];
    const float* gb2 = (const float*)d_in[10];
    float* out = (float*)d_out;

    const int NB = (NN + 255) / 256;   // 196 scan blocks

    auto al = [](size_t v) { return (v + 255) & ~(size_t)255; };
    const size_t o_cnt  = 0;
    const size_t o_excl = al(o_cnt + (size_t)NN * 4);
    const size_t o_off  = al(o_excl + (size_t)NN * 4);
    const size_t o_cur  = al(o_off + (size_t)(NN + 1) * 4);
    const size_t o_bsum = al(o_cur + (size_t)NN * 4);
    const size_t o_bexc = al(o_bsum + (size_t)NB * 4);
    const size_t o_w2t  = al(o_bexc + (size_t)NB * 4);
    const size_t o_eid  = al(o_w2t + (size_t)64 * 64 * 2);
    const size_t o_msg  = al(o_eid + (size_t)NE * 4);
    const size_t need   = o_msg + (size_t)NE * 64 * 2;

    if (ws_size >= need) {
        char* w = (char*)d_ws;
        u32*    cnt  = (u32*)(w + o_cnt);
        u32*    excl = (u32*)(w + o_excl);
        u32*    off  = (u32*)(w + o_off);
        u32*    cur  = (u32*)(w + o_cur);
        u32*    bsum = (u32*)(w + o_bsum);
        u32*    bexc = (u32*)(w + o_bexc);
        __half* w2t  = (__half*)(w + o_w2t);
        u32*    eid  = (u32*)(w + o_eid);
        __half* msg  = (__half*)(w + o_msg);

        zero_u32_kernel<<<NB, 256, 0, stream>>>(cnt, NN);
        prep_w2t_kernel<<<16, 256, 0, stream>>>(fw2, w2t);
        hist_kernel<<<NE / 256, 256, 0, stream>>>(ei, cnt);
        scan1_kernel<<<NB, 256, 0, stream>>>(cnt, excl, bsum);
        scan2_kernel<<<1, 256, 0, stream>>>(bsum, bexc, NB);
        scan3_kernel<<<NB, 256, 0, stream>>>(excl, bexc, off, cur);
        scatter_kernel<<<NE / 256, 256, 0, stream>>>(ei, cur, eid);
        edge_mfma_kernel<<<NE / 256, 256, 0, stream>>>(x, pos, ei, eid,
                                                       fw1, fb1, w2t, fb2, msg);
        gather_kernel<<<(NN + 7) / 8, 256, 0, stream>>>(msg, off, out);
        node_kernel<<<(NN + 255) / 256, 256, 0, stream>>>(x, out, gw1, gb1, gw2, gb2);
    } else {
        // fallback: atomic path (ws too small for message materialization)
        const int n4 = NN * 64 / 4;
        zero_kernel<<<(n4 + 255) / 256, 256, 0, stream>>>((float4*)out, n4);
        edge_atomic_kernel<<<NE / 256, 256, 0, stream>>>(x, pos, ei, fw1, fb1,
                                                         fw2, fb2, (unsigned int*)out);
        node_kernel<<<(NN + 255) / 256, 256, 0, stream>>>(x, out, gw1, gb1, gw2, gb2);
    }
}